// Round 1
// baseline (205.335 us; speedup 1.0000x reference)
//
#include <hip/hip_runtime.h>

// Problem constants: B=4, C=256, HS=WS=64 -> N=4096 pixels/batch, 16384 total.
// NK=NV=32, NH=8, QKV = 32*32+32+32 = 1088, NH*QKV = 8704.
#define NPIX_TOTAL 16384
#define CDIM 256
#define NHEADS 8
#define QKVD 1088
#define NQKV 8704

typedef unsigned short u16;
typedef __attribute__((ext_vector_type(8))) __bf16 bf16x8;
typedef __attribute__((ext_vector_type(4))) float f32x4;

__device__ static inline u16 f2bf(float f) {
  union { float f; unsigned u; } x; x.f = f;
  unsigned r = x.u + 0x7fffu + ((x.u >> 16) & 1u);   // round-to-nearest-even
  return (u16)(r >> 16);
}
__device__ static inline float bf2f(u16 b) {
  union { unsigned u; float f; } x; x.u = ((unsigned)b) << 16;
  return x.f;
}

// async global->LDS, 16B per lane; LDS dest must be wave-uniform base (+lane*16 by HW)
__device__ static inline void gload_lds16(const void* g, void* l) {
  __builtin_amdgcn_global_load_lds((const __attribute__((address_space(1))) void*)g,
                                   (__attribute__((address_space(3))) void*)l,
                                   16, 0, 0);
}

// ---------------------------------------------------------------------------
// x (B, C, 4096) f32  ->  Xbf (B*4096, 256) bf16   (transpose via LDS tile)
__global__ __launch_bounds__(256) void transpose_cast(const float* __restrict__ x,
                                                      u16* __restrict__ xt) {
  __shared__ float t[64][65];
  const int b = blockIdx.z;
  const float* xb = x + (size_t)b * CDIM * 4096;
  u16* ob = xt + (size_t)b * 4096 * CDIM;
  const int n0 = blockIdx.x * 64;
  const int c0 = blockIdx.y * 64;
  const int tx = threadIdx.x & 63;
  const int ty = threadIdx.x >> 6;
#pragma unroll
  for (int i = 0; i < 16; ++i)
    t[ty + i * 4][tx] = xb[(size_t)(c0 + ty + i * 4) * 4096 + n0 + tx];
  __syncthreads();
#pragma unroll
  for (int i = 0; i < 16; ++i)
    ob[(size_t)(n0 + ty + i * 4) * CDIM + c0 + tx] = f2bf(t[tx][ty + i * 4]);
}

// f32 -> bf16 elementwise (n divisible by 1024 per launch config)
__global__ __launch_bounds__(256) void cast_bf(const float* __restrict__ in,
                                               u16* __restrict__ out, int n) {
  const int i = (blockIdx.x * 256 + threadIdx.x) * 4;
  if (i >= n) return;
  const f32x4 v = *(const f32x4*)(in + i);
  u16 o0 = f2bf(v.x), o1 = f2bf(v.y), o2 = f2bf(v.z), o3 = f2bf(v.w);
  unsigned p0 = (unsigned)o0 | ((unsigned)o1 << 16);
  unsigned p1 = (unsigned)o2 | ((unsigned)o3 << 16);
  *(unsigned*)(out + i) = p0;
  *(unsigned*)(out + i + 2) = p1;
}

// ---------------------------------------------------------------------------
// NT GEMM: C[m][n] = sum_k A[m][k]*B[n][k], K=256 fixed, bf16 in, f32 acc.
// 128x128 tile, BK=64, 256 threads = 4 waves (2x2 of 64x64), 16x16x32 MFMA.
// EPI=0: store bf16 C row-major, ld=ldc (qkv).
// EPI=1: out f32 (B,C,4096): out[(b*256+n)*4096 + pix] = acc + bias[n],
//        with b = gm>>12, pix = gm&4095 (gm = global pixel row).
template <int EPI>
__global__ __launch_bounds__(256, 2) void gemm_nt(const u16* __restrict__ A,
                                                  const u16* __restrict__ B,
                                                  void* __restrict__ Cout,
                                                  const float* __restrict__ bias,
                                                  int ldc) {
  __shared__ u16 As[128 * 64];
  __shared__ u16 Bs[128 * 64];
  const int tid = threadIdx.x;
  const int lane = tid & 63;
  const int wv = tid >> 6;
  const size_t m0 = (size_t)blockIdx.y * 128;
  const size_t n0 = (size_t)blockIdx.x * 128;
  const int wm = (wv >> 1) * 64;
  const int wn = (wv & 1) * 64;
  const int frow = lane & 15;
  const int fk = (lane >> 4) * 8;

  f32x4 acc[4][4] = {};

#pragma unroll 1
  for (int kt = 0; kt < 4; ++kt) {
    const int k0 = kt * 64;
    __syncthreads();  // previous compute done before LDS overwrite
#pragma unroll
    for (int i = 0; i < 4; ++i) {
      const int ci = (i * 4 + wv) * 64 + lane;  // 16B chunk id, 0..1023
      const int r = ci >> 3;
      const int c8 = (ci & 7) * 8;
      gload_lds16(A + (m0 + r) * CDIM + k0 + c8, (char*)As + (size_t)(i * 4 + wv) * 1024);
      gload_lds16(B + (n0 + r) * CDIM + k0 + c8, (char*)Bs + (size_t)(i * 4 + wv) * 1024);
    }
    __syncthreads();  // vmcnt(0) drain at barrier
#pragma unroll
    for (int kk = 0; kk < 64; kk += 32) {
      bf16x8 af[4], bfr[4];
#pragma unroll
      for (int mi = 0; mi < 4; ++mi)
        af[mi] = *(const bf16x8*)(As + (wm + mi * 16 + frow) * 64 + kk + fk);
#pragma unroll
      for (int ni = 0; ni < 4; ++ni)
        bfr[ni] = *(const bf16x8*)(Bs + (wn + ni * 16 + frow) * 64 + kk + fk);
#pragma unroll
      for (int mi = 0; mi < 4; ++mi)
#pragma unroll
        for (int ni = 0; ni < 4; ++ni)
          acc[mi][ni] =
              __builtin_amdgcn_mfma_f32_16x16x32_bf16(af[mi], bfr[ni], acc[mi][ni], 0, 0, 0);
    }
  }

  // D layout (m89-verified): col = lane&15, row = (lane>>4)*4 + j
  if (EPI == 0) {
    u16* C = (u16*)Cout;
#pragma unroll
    for (int mi = 0; mi < 4; ++mi)
#pragma unroll
      for (int ni = 0; ni < 4; ++ni) {
        const size_t gm = m0 + wm + mi * 16 + ((lane >> 4) * 4);
        const size_t gn = n0 + wn + ni * 16 + (lane & 15);
#pragma unroll
        for (int j = 0; j < 4; ++j)
          C[(gm + j) * (size_t)ldc + gn] = f2bf(acc[mi][ni][j]);
      }
  } else {
    float* C = (float*)Cout;
#pragma unroll
    for (int mi = 0; mi < 4; ++mi)
#pragma unroll
      for (int ni = 0; ni < 4; ++ni) {
        const size_t gm = m0 + wm + mi * 16 + ((lane >> 4) * 4);
        const size_t gn = n0 + wn + ni * 16 + (lane & 15);
        f32x4 v = acc[mi][ni];
        v += bias[gn];
        const size_t b = gm >> 12;
        const size_t pix = gm & 4095;
        *(f32x4*)(C + ((b << 8) + gn) * 4096 + pix) = v;  // 4 consecutive pixels
      }
  }
}

// ---------------------------------------------------------------------------
// Per-pixel attention: one wave per pixel. lane -> v = lane&31, khalf = lane>>5.
// qk[v] = sum_k q[k]*K[k][v]/sqrt(32); softmax over v (32 lanes); a = p*vvec.
__global__ __launch_bounds__(256) void attn_k(const u16* __restrict__ qkv,
                                              u16* __restrict__ aout) {
  const int lane = threadIdx.x & 63;
  const int wv = threadIdx.x >> 6;
  const size_t p = (size_t)blockIdx.x * 4 + wv;
  const u16* row = qkv + p * NQKV;
  const int v = lane & 31;
  const int kh = lane >> 5;
#pragma unroll 1
  for (int h = 0; h < NHEADS; ++h) {
    const u16* base = row + h * QKVD;
    const float qv = bf2f(base[v]);          // lane holds q[lane&31]
    const float vv = bf2f(base[1056 + v]);
    float part = 0.f;
#pragma unroll
    for (int i = 0; i < 16; ++i) {
      const int k = kh * 16 + i;
      const float qk = __shfl(qv, k);        // q[k] lives on lane k
      part = fmaf(qk, bf2f(base[32 + k * 32 + v]), part);
    }
    part += __shfl_xor(part, 32);            // combine k-halves
    const float s = part * 0.17677669529663687f;  // 1/sqrt(32)
    float mx = s;
#pragma unroll
    for (int off = 16; off; off >>= 1) mx = fmaxf(mx, __shfl_xor(mx, off));
    const float e = __expf(s - mx);
    float sum = e;
#pragma unroll
    for (int off = 16; off; off >>= 1) sum += __shfl_xor(sum, off);
    const float r = e / sum * vv;
    if (lane < 32) aout[p * 256 + h * 32 + v] = f2bf(r);
  }
}

// ---------------------------------------------------------------------------
extern "C" void kernel_launch(void* const* d_in, const int* in_sizes, int n_in,
                              void* d_out, int out_size, void* d_ws, size_t ws_size,
                              hipStream_t stream) {
  (void)in_sizes; (void)n_in; (void)out_size;
  const float* x = (const float*)d_in[0];     // (4, 256, 64, 64)
  const float* Wqkv = (const float*)d_in[1];  // (8, 1088, 256)
  const float* Wc = (const float*)d_in[2];    // (256, 256)
  const float* bc = (const float*)d_in[3];    // (256,)
  float* out = (float*)d_out;                 // (4, 256, 64, 64)
  char* ws = (char*)d_ws;

  // workspace layout (bytes)
  const size_t XBF_OFF = 0;                        // 16384*256*2  = 8388608
  const size_t WBF_OFF = 8388608;                  // 8704*256*2   = 4456448
  const size_t WCBF_OFF = 12845056;                // 256*256*2    = 131072
  const size_t ABF_OFF = 12976128;                 // 16384*256*2  = 8388608
  const size_t QKV_OFF = 21364736;                 // chunk*8704*2
  u16* Xbf = (u16*)(ws + XBF_OFF);
  u16* Wbf = (u16*)(ws + WBF_OFF);
  u16* Wcbf = (u16*)(ws + WCBF_OFF);
  u16* Abf = (u16*)(ws + ABF_OFF);
  u16* Qkv = (u16*)(ws + QKV_OFF);

  // pick largest pixel-chunk whose qkv slab fits the workspace
  size_t avail = (ws_size > QKV_OFF) ? (ws_size - QKV_OFF) : 0;
  int chunk = 4096;
  while (chunk > 128 && (size_t)chunk * NQKV * 2 > avail) chunk >>= 1;
  const int nchunks = NPIX_TOTAL / chunk;

  // stage 0: convert inputs to bf16
  transpose_cast<<<dim3(64, 4, 4), 256, 0, stream>>>(x, Xbf);
  cast_bf<<<(NQKV * CDIM) / 1024, 256, 0, stream>>>(Wqkv, Wbf, NQKV * CDIM);
  cast_bf<<<(CDIM * 256) / 1024, 256, 0, stream>>>(Wc, Wcbf, CDIM * 256);

  // stage 1+2: qkv GEMM then per-pixel attention, chunked over pixels
  for (int c = 0; c < nchunks; ++c) {
    const size_t p0 = (size_t)c * chunk;
    gemm_nt<0><<<dim3(NQKV / 128, chunk / 128), 256, 0, stream>>>(
        Xbf + p0 * CDIM, Wbf, Qkv, nullptr, NQKV);
    attn_k<<<chunk / 4, 256, 0, stream>>>(Qkv, Abf + p0 * 256);
  }

  // stage 3: out = a @ Wc^T + bc, written transposed to (B, C, 4096)
  gemm_nt<1><<<dim3(256 / 128, NPIX_TOTAL / 128), 256, 0, stream>>>(
      Abf, Wcbf, out, bc, 4096);
}